// Round 4
// baseline (701.174 us; speedup 1.0000x reference)
//
#include <hip/hip_runtime.h>
#include <cstdint>
#include <cstddef>

typedef unsigned short u16;
typedef unsigned int u32;

typedef unsigned short u16x8 __attribute__((ext_vector_type(8)));
typedef __bf16 bf16x8 __attribute__((ext_vector_type(8)));
typedef float f32x4 __attribute__((ext_vector_type(4)));
typedef float f32x8 __attribute__((ext_vector_type(8)));

#define NB   128
#define NL   192
#define NTOK (NB * NL)   // 24576
#define DIM  512
#define HID  2048

static __device__ __forceinline__ float bf2f(u16 h) {
    union { u32 u; float f; } v; v.u = ((u32)h) << 16; return v.f;
}
static __device__ __forceinline__ u16 f2bf(float f) {
    union { float f; u32 u; } v; v.f = f;
    u32 u = v.u + 0x7FFF + ((v.u >> 16) & 1);  // RNE
    return (u16)(u >> 16);
}

// -------- weight transpose + cast: in f32 (K,N) -> out bf16 (N,K) --------
__global__ void transpose_f2b(const float* __restrict__ in, u16* __restrict__ out,
                              int K, int N) {
    __shared__ float tile[32][33];
    int tx = threadIdx.x & 31, ty = threadIdx.x >> 5;  // 32 x 8
    int n0 = blockIdx.x * 32, k0 = blockIdx.y * 32;
#pragma unroll
    for (int i = 0; i < 4; i++)
        tile[ty + i * 8][tx] = in[(size_t)(k0 + ty + i * 8) * N + n0 + tx];
    __syncthreads();
#pragma unroll
    for (int i = 0; i < 4; i++)
        out[(size_t)(n0 + ty + i * 8) * K + k0 + tx] = f2bf(tile[tx][ty + i * 8]);
}

// -------- embedding: emb[t=l*B+b][d] = sum of 5 f32 tables; f32 + bf16 out ----
static __device__ __forceinline__ void add8f(float* acc, const float* p) {
    f32x8 v = *(const f32x8*)p;
#pragma unroll
    for (int i = 0; i < 8; i++) acc[i] += v[i];
}

__global__ void embed_kernel(const int* __restrict__ element, const int* __restrict__ aroma,
                             const int* __restrict__ charge, const int* __restrict__ segment,
                             const float* __restrict__ pe, const float* __restrict__ E_elem,
                             const float* __restrict__ E_charge, const float* __restrict__ E_aroma,
                             const float* __restrict__ E_seg,
                             float* __restrict__ emb32, u16* __restrict__ emb16) {
    int t = blockIdx.x * 4 + (threadIdx.x >> 6);  // one wave per token
    int lane = threadIdx.x & 63;
    int l = t >> 7, b = t & 127;                  // t = l*128 + b
    int d = lane * 8;
    int idx = b * NL + l;
    int e = element[idx];
    int a = aroma[idx];
    int c = charge[idx] + 6;
    int s = segment[idx];
    float acc[8] = {0, 0, 0, 0, 0, 0, 0, 0};
    add8f(acc, E_elem  + (size_t)e * DIM + d);
    add8f(acc, pe      + (size_t)l * DIM + d);
    add8f(acc, E_aroma + (size_t)a * DIM + d);
    add8f(acc, E_charge+ (size_t)c * DIM + d);
    add8f(acc, E_seg   + (size_t)s * DIM + d);
    f32x8 o32; u16x8 o16;
#pragma unroll
    for (int i = 0; i < 8; i++) { o32[i] = acc[i]; o16[i] = f2bf(acc[i]); }
    *(f32x8*)(emb32 + (size_t)t * DIM + d) = o32;
    *(u16x8*)(emb16 + (size_t)t * DIM + d) = o16;
}

// -------- GEMM: C[M,N] = A[M,K] @ BT[N,K]^T (+f32 bias, relu, bf16/f32 resid) --
// m97 structure: 128x128 tile, BK=32, 4 waves (2x2 quadrants), 4x4
// mfma_f32_16x16x32_bf16 per wave, global_load_lds width=16 staging
// (wave-uniform LDS base + lane*16B; LDS row stride 32 u16 — no padding,
// required by the lane->LDS contiguity contract).
__global__ __launch_bounds__(256) void gemm_bt(
    const u16* __restrict__ A, const u16* __restrict__ BT,
    const float* __restrict__ bias, const u16* __restrict__ resid16,
    const float* __restrict__ resid32,
    u16* __restrict__ C, int M, int N, int K, int do_relu) {
    __shared__ __align__(16) u16 As[128 * 32];
    __shared__ __align__(16) u16 Bs[128 * 32];

    const int tid  = threadIdx.x;
    const int wave = tid >> 6;
    const int lane = tid & 63;
    const int m0 = blockIdx.x * 128;
    const int n0 = blockIdx.y * 128;
    const int wm = (wave >> 1) * 64;   // wave's 64x64 quadrant
    const int wn = (wave & 1) * 64;
    const int lr = lane >> 2;          // staging: row within 16-row group
    const int lc = (lane & 3) * 8;     // staging: k-chunk (8 bf16 = 16 B)
    const int fr = lane & 15;          // fragment row/col
    const int fq = lane >> 4;          // fragment k-quad

    f32x4 acc[4][4] = {};

    // wave w stages rows [w*16, w*16+16) and [64+w*16, ...) of each tile
    const u16* Ag0 = A  + (size_t)(m0 + wave * 16 + lr) * K + lc;
    const u16* Ag1 = Ag0 + (size_t)64 * K;
    const u16* Bg0 = BT + (size_t)(n0 + wave * 16 + lr) * K + lc;
    const u16* Bg1 = Bg0 + (size_t)64 * K;
    u16* As0 = As + (wave * 16) * 32;        // wave-uniform LDS bases
    u16* As1 = As + (64 + wave * 16) * 32;
    u16* Bs0 = Bs + (wave * 16) * 32;
    u16* Bs1 = Bs + (64 + wave * 16) * 32;

    for (int k0 = 0; k0 < K; k0 += 32) {
        __builtin_amdgcn_global_load_lds(
            (const __attribute__((address_space(1))) void*)(Ag0 + k0),
            (__attribute__((address_space(3))) void*)As0, 16, 0, 0);
        __builtin_amdgcn_global_load_lds(
            (const __attribute__((address_space(1))) void*)(Ag1 + k0),
            (__attribute__((address_space(3))) void*)As1, 16, 0, 0);
        __builtin_amdgcn_global_load_lds(
            (const __attribute__((address_space(1))) void*)(Bg0 + k0),
            (__attribute__((address_space(3))) void*)Bs0, 16, 0, 0);
        __builtin_amdgcn_global_load_lds(
            (const __attribute__((address_space(1))) void*)(Bg1 + k0),
            (__attribute__((address_space(3))) void*)Bs1, 16, 0, 0);
        __syncthreads();  // vmcnt(0) drain + barrier

        bf16x8 af[4], bg[4];
#pragma unroll
        for (int i = 0; i < 4; i++)
            af[i] = *(const bf16x8*)(As + (wm + i * 16 + fr) * 32 + fq * 8);
#pragma unroll
        for (int j = 0; j < 4; j++)
            bg[j] = *(const bf16x8*)(Bs + (wn + j * 16 + fr) * 32 + fq * 8);
#pragma unroll
        for (int i = 0; i < 4; i++)
#pragma unroll
            for (int j = 0; j < 4; j++)
                acc[i][j] = __builtin_amdgcn_mfma_f32_16x16x32_bf16(
                    af[i], bg[j], acc[i][j], 0, 0, 0);
        __syncthreads();
    }

    // epilogue: C/D layout col = lane&15 (n), row = (lane>>4)*4 + reg (m)
#pragma unroll
    for (int j = 0; j < 4; j++) {
        int n = n0 + wn + j * 16 + fr;
        float bv = bias[n];
#pragma unroll
        for (int i = 0; i < 4; i++) {
#pragma unroll
            for (int r = 0; r < 4; r++) {
                int m = m0 + wm + i * 16 + fq * 4 + r;
                float v = acc[i][j][r] + bv;
                if (do_relu) v = fmaxf(v, 0.0f);
                if (resid16) v += bf2f(resid16[(size_t)m * N + n]);
                if (resid32) v += resid32[(size_t)m * N + n];
                C[(size_t)m * N + n] = f2bf(v);
            }
        }
    }
}

// -------- aggregation + final residual (in-place on d_out, f32) --------
// out[t=l*B+b][d] = emb32[t][d] + sum_m (bond[b,l,m]!=l) * msg[bond*B+b][d]
__global__ void agg_kernel(const float* __restrict__ emb32, const u16* __restrict__ msg,
                           const int* __restrict__ bond, float* __restrict__ out) {
    int t = blockIdx.x * 4 + (threadIdx.x >> 6);  // one wave per token
    int lane = threadIdx.x & 63;
    int l = t >> 7, b = t & 127;
    int d = lane * 8;
    float acc[8];
    {
        f32x8 v = *(const f32x8*)(emb32 + (size_t)t * DIM + d);
#pragma unroll
        for (int i = 0; i < 8; i++) acc[i] = v[i];
    }
    const int* bp = bond + ((size_t)b * NL + l) * 6;
#pragma unroll
    for (int m = 0; m < 6; m++) {
        int j = bp[m];
        if (j != l) {  // wave-uniform branch
            u16x8 g = *(const u16x8*)(msg + ((size_t)j * NB + b) * DIM + d);
#pragma unroll
            for (int i = 0; i < 8; i++) acc[i] += bf2f(g[i]);
        }
    }
    f32x8 o;
#pragma unroll
    for (int i = 0; i < 8; i++) o[i] = acc[i];
    *(f32x8*)(out + (size_t)t * DIM + d) = o;
}

extern "C" void kernel_launch(void* const* d_in, const int* in_sizes, int n_in,
                              void* d_out, int out_size, void* d_ws, size_t ws_size,
                              hipStream_t stream) {
    const int* element = (const int*)d_in[0];
    const int* bond    = (const int*)d_in[1];
    const int* aroma   = (const int*)d_in[2];
    const int* charge  = (const int*)d_in[3];
    const int* segment = (const int*)d_in[4];
    const float* pe      = (const float*)d_in[5];
    const float* E_elem  = (const float*)d_in[6];
    const float* E_charge= (const float*)d_in[7];
    const float* E_aroma = (const float*)d_in[8];
    const float* E_seg   = (const float*)d_in[9];
    const float* W1 = (const float*)d_in[10];
    const float* b1 = (const float*)d_in[11];
    const float* W2 = (const float*)d_in[12];
    const float* b2 = (const float*)d_in[13];
    const float* W3 = (const float*)d_in[14];
    const float* b3 = (const float*)d_in[15];
    const float* W4 = (const float*)d_in[16];
    const float* b4 = (const float*)d_in[17];
    const float* W5 = (const float*)d_in[18];
    const float* b5 = (const float*)d_in[19];

    // f32 emb lives in d_out (50 MiB); agg rewrites d_out in place at the end.
    float* emb32 = (float*)d_out;

    // dynamic ws layout — never exceed ws_size
    char* ws = (char*)d_ws;
    size_t woff = 0;
    auto take = [&](size_t bytes) -> u16* {
        u16* p = (u16*)(ws + woff);
        woff += (bytes + 255) & ~(size_t)255;
        return p;
    };
    u16* W1T = take((size_t)HID * DIM * 2);   // 2048x512 bf16
    u16* W2T = take((size_t)DIM * HID * 2);   // 512x2048
    u16* W3T = take((size_t)HID * DIM * 2);
    u16* W4T = take((size_t)DIM * HID * 2);
    u16* W5T = take((size_t)DIM * DIM * 2);
    u16* emb16 = take((size_t)NTOK * DIM * 2);  // 24 MiB
    u16* msg   = take((size_t)NTOK * DIM * 2);  // 24 MiB

    // pick largest M-chunk that fits: h(CM x HID) + xa,xb(CM x DIM), bf16
    static const int ncs[] = {1, 2, 3, 4, 6, 8, 12, 16, 24, 32, 48, 64, 96, 192};
    int CM = 128;
    for (int nc : ncs) {
        int cm = NTOK / nc;
        size_t need = woff + ((size_t)cm * HID * 2 + 256)
                           + ((size_t)cm * DIM * 2 + 256) * 2;
        if (need <= ws_size) { CM = cm; break; }
    }
    u16* hC  = take((size_t)CM * HID * 2);
    u16* xaC = take((size_t)CM * DIM * 2);
    u16* xbC = take((size_t)CM * DIM * 2);

    // weight transposes + cast: f32 (K,N) -> bf16 (N,K)
    transpose_f2b<<<dim3(HID / 32, DIM / 32), 256, 0, stream>>>(W1, W1T, DIM, HID);
    transpose_f2b<<<dim3(DIM / 32, HID / 32), 256, 0, stream>>>(W2, W2T, HID, DIM);
    transpose_f2b<<<dim3(HID / 32, DIM / 32), 256, 0, stream>>>(W3, W3T, DIM, HID);
    transpose_f2b<<<dim3(DIM / 32, HID / 32), 256, 0, stream>>>(W4, W4T, HID, DIM);
    transpose_f2b<<<dim3(DIM / 32, DIM / 32), 256, 0, stream>>>(W5, W5T, DIM, DIM);

    embed_kernel<<<NTOK / 4, 256, 0, stream>>>(element, aroma, charge, segment, pe,
                                               E_elem, E_charge, E_aroma, E_seg,
                                               emb32, emb16);

    // MLP per M-chunk: x += relu(x@W1+b1)@W2+b2 ; x += relu(x@W3+b3)@W4+b4 ; msg = x@W5+b5
    for (int c0 = 0; c0 < NTOK; c0 += CM) {
        const u16* x16 = emb16 + (size_t)c0 * DIM;
        const float* x32 = emb32 + (size_t)c0 * DIM;
        u16* msgC = msg + (size_t)c0 * DIM;
        gemm_bt<<<dim3(CM / 128, HID / 128), 256, 0, stream>>>(x16, W1T, b1, nullptr, nullptr, hC,  CM, HID, DIM, 1);
        gemm_bt<<<dim3(CM / 128, DIM / 128), 256, 0, stream>>>(hC,  W2T, b2, nullptr, x32,     xaC, CM, DIM, HID, 0);
        gemm_bt<<<dim3(CM / 128, HID / 128), 256, 0, stream>>>(xaC, W3T, b3, nullptr, nullptr, hC,  CM, HID, DIM, 1);
        gemm_bt<<<dim3(CM / 128, DIM / 128), 256, 0, stream>>>(hC,  W4T, b4, xaC,    nullptr,  xbC, CM, DIM, HID, 0);
        gemm_bt<<<dim3(CM / 128, DIM / 128), 256, 0, stream>>>(xbC, W5T, b5, nullptr, nullptr, msgC, CM, DIM, DIM, 0);
    }

    agg_kernel<<<NTOK / 4, 256, 0, stream>>>(emb32, msg, bond, (float*)d_out);
}

// Round 5
// 613.768 us; speedup vs baseline: 1.1424x; 1.1424x over previous
//
#include <hip/hip_runtime.h>
#include <cstdint>
#include <cstddef>

typedef unsigned short u16;
typedef unsigned int u32;

typedef unsigned short u16x8 __attribute__((ext_vector_type(8)));
typedef __bf16 bf16x8 __attribute__((ext_vector_type(8)));
typedef float f32x4 __attribute__((ext_vector_type(4)));
typedef float f32x8 __attribute__((ext_vector_type(8)));

#define NB   128
#define NL   192
#define NTOK (NB * NL)   // 24576
#define DIM  512
#define HID  2048

static __device__ __forceinline__ float bf2f(u16 h) {
    union { u32 u; float f; } v; v.u = ((u32)h) << 16; return v.f;
}
static __device__ __forceinline__ u16 f2bf(float f) {
    union { float f; u32 u; } v; v.f = f;
    u32 u = v.u + 0x7FFF + ((v.u >> 16) & 1);  // RNE
    return (u16)(u >> 16);
}

// -------- weight transpose + cast: in f32 (K,N) -> out bf16 (N,K) --------
__global__ void transpose_f2b(const float* __restrict__ in, u16* __restrict__ out,
                              int K, int N) {
    __shared__ float tile[32][33];
    int tx = threadIdx.x & 31, ty = threadIdx.x >> 5;  // 32 x 8
    int n0 = blockIdx.x * 32, k0 = blockIdx.y * 32;
#pragma unroll
    for (int i = 0; i < 4; i++)
        tile[ty + i * 8][tx] = in[(size_t)(k0 + ty + i * 8) * N + n0 + tx];
    __syncthreads();
#pragma unroll
    for (int i = 0; i < 4; i++)
        out[(size_t)(n0 + ty + i * 8) * K + k0 + tx] = f2bf(tile[tx][ty + i * 8]);
}

// -------- embedding: emb[t=l*B+b][d] = sum of 5 f32 tables; f32 + bf16 out ----
static __device__ __forceinline__ void add8f(float* acc, const float* p) {
    f32x8 v = *(const f32x8*)p;
#pragma unroll
    for (int i = 0; i < 8; i++) acc[i] += v[i];
}

__global__ void embed_kernel(const int* __restrict__ element, const int* __restrict__ aroma,
                             const int* __restrict__ charge, const int* __restrict__ segment,
                             const float* __restrict__ pe, const float* __restrict__ E_elem,
                             const float* __restrict__ E_charge, const float* __restrict__ E_aroma,
                             const float* __restrict__ E_seg,
                             float* __restrict__ emb32, u16* __restrict__ emb16) {
    int t = blockIdx.x * 4 + (threadIdx.x >> 6);  // one wave per token
    int lane = threadIdx.x & 63;
    int l = t >> 7, b = t & 127;                  // t = l*128 + b
    int d = lane * 8;
    int idx = b * NL + l;
    int e = element[idx];
    int a = aroma[idx];
    int c = charge[idx] + 6;
    int s = segment[idx];
    float acc[8] = {0, 0, 0, 0, 0, 0, 0, 0};
    add8f(acc, E_elem  + (size_t)e * DIM + d);
    add8f(acc, pe      + (size_t)l * DIM + d);
    add8f(acc, E_aroma + (size_t)a * DIM + d);
    add8f(acc, E_charge+ (size_t)c * DIM + d);
    add8f(acc, E_seg   + (size_t)s * DIM + d);
    f32x8 o32; u16x8 o16;
#pragma unroll
    for (int i = 0; i < 8; i++) { o32[i] = acc[i]; o16[i] = f2bf(acc[i]); }
    *(f32x8*)(emb32 + (size_t)t * DIM + d) = o32;
    *(u16x8*)(emb16 + (size_t)t * DIM + d) = o16;
}

// -------- GEMM: C[M,N] = A[M,K] @ BT[N,K]^T (+f32 bias, relu, bf16/f32 resid) --
// Double-buffered LDS ping-pong (AITER-style): global_load_lds width=16 into
// buf[(k+2)&1] stays IN FLIGHT across the barrier; each wave waits only its
// own 4 oldest loads (s_waitcnt vmcnt(4)), then raw s_barrier. No vmcnt(0)
// drain per iteration — that drain was the 155us/13%-MfmaUtil bottleneck.
__global__ __launch_bounds__(256) void gemm_bt(
    const u16* __restrict__ A, const u16* __restrict__ BT,
    const float* __restrict__ bias, const u16* __restrict__ resid16,
    const float* __restrict__ resid32,
    u16* __restrict__ C, int M, int N, int K, int do_relu) {
    __shared__ __align__(16) u16 As[2][128 * 32];
    __shared__ __align__(16) u16 Bs[2][128 * 32];

    const int tid  = threadIdx.x;
    const int wave = tid >> 6;
    const int lane = tid & 63;
    const int m0 = blockIdx.x * 128;
    const int n0 = blockIdx.y * 128;
    const int wm = (wave >> 1) * 64;   // wave's 64x64 quadrant
    const int wn = (wave & 1) * 64;
    const int lr = lane >> 2;          // staging: row within 16-row group
    const int lc = (lane & 3) * 8;     // staging: k-chunk (8 bf16 = 16 B)
    const int fr = lane & 15;          // fragment row/col
    const int fq = lane >> 4;          // fragment k-quad

    f32x4 acc[4][4] = {};

    // wave w stages rows [w*16, w*16+16) and [64+w*16, ...) of each tile
    const u16* Ag0 = A  + (size_t)(m0 + wave * 16 + lr) * K + lc;
    const u16* Ag1 = Ag0 + (size_t)64 * K;
    const u16* Bg0 = BT + (size_t)(n0 + wave * 16 + lr) * K + lc;
    const u16* Bg1 = Bg0 + (size_t)64 * K;
    const int stA0 = (wave * 16) * 32;        // wave-uniform LDS offsets (u16)
    const int stA1 = (64 + wave * 16) * 32;

#define STAGE(buf, k0) do {                                                     \
    __builtin_amdgcn_global_load_lds(                                           \
        (const __attribute__((address_space(1))) void*)(Ag0 + (k0)),            \
        (__attribute__((address_space(3))) void*)(&As[buf][stA0]), 16, 0, 0);   \
    __builtin_amdgcn_global_load_lds(                                           \
        (const __attribute__((address_space(1))) void*)(Ag1 + (k0)),            \
        (__attribute__((address_space(3))) void*)(&As[buf][stA1]), 16, 0, 0);   \
    __builtin_amdgcn_global_load_lds(                                           \
        (const __attribute__((address_space(1))) void*)(Bg0 + (k0)),            \
        (__attribute__((address_space(3))) void*)(&Bs[buf][stA0]), 16, 0, 0);   \
    __builtin_amdgcn_global_load_lds(                                           \
        (const __attribute__((address_space(1))) void*)(Bg1 + (k0)),            \
        (__attribute__((address_space(3))) void*)(&Bs[buf][stA1]), 16, 0, 0);   \
} while (0)

    const int kIters = K >> 5;
    STAGE(0, 0);          // tile 0 -> buf 0   (4 loads in flight)
    STAGE(1, 32);         // tile 1 -> buf 1   (8 in flight)

    for (int k = 0; k < kIters; ++k) {
        const int cur = k & 1;
        // wait own 4 oldest loads (tile k) only; tile k+1's 4 stay in flight.
        asm volatile("s_waitcnt vmcnt(4)\n\ts_barrier" ::: "memory");

        bf16x8 af[4], bg[4];
#pragma unroll
        for (int i = 0; i < 4; i++)
            af[i] = *(const bf16x8*)(&As[cur][(wm + i * 16 + fr) * 32 + fq * 8]);
#pragma unroll
        for (int j = 0; j < 4; j++)
            bg[j] = *(const bf16x8*)(&Bs[cur][(wn + j * 16 + fr) * 32 + fq * 8]);
#pragma unroll
        for (int i = 0; i < 4; i++)
#pragma unroll
            for (int j = 0; j < 4; j++)
                acc[i][j] = __builtin_amdgcn_mfma_f32_16x16x32_bf16(
                    af[i], bg[j], acc[i][j], 0, 0, 0);

        // all waves done reading buf cur -> safe to overwrite with tile k+2.
        asm volatile("s_barrier" ::: "memory");
        // dummy reload of tile 0 on the tail keeps vmcnt bookkeeping uniform;
        // it targets a buffer that is never read again.
        const int knext = (k + 2 < kIters) ? (k + 2) << 5 : 0;
        STAGE(cur, knext);
    }
#undef STAGE

    // epilogue: C/D layout col = lane&15 (n), row = (lane>>4)*4 + reg (m)
#pragma unroll
    for (int j = 0; j < 4; j++) {
        int n = n0 + wn + j * 16 + fr;
        float bv = bias[n];
#pragma unroll
        for (int i = 0; i < 4; i++) {
#pragma unroll
            for (int r = 0; r < 4; r++) {
                int m = m0 + wm + i * 16 + fq * 4 + r;
                float v = acc[i][j][r] + bv;
                if (do_relu) v = fmaxf(v, 0.0f);
                if (resid16) v += bf2f(resid16[(size_t)m * N + n]);
                if (resid32) v += resid32[(size_t)m * N + n];
                C[(size_t)m * N + n] = f2bf(v);
            }
        }
    }
}

// -------- aggregation + final residual (in-place on d_out, f32) --------
// out[t=l*B+b][d] = emb32[t][d] + sum_m (bond[b,l,m]!=l) * msg[bond*B+b][d]
__global__ void agg_kernel(const float* __restrict__ emb32, const u16* __restrict__ msg,
                           const int* __restrict__ bond, float* __restrict__ out) {
    int t = blockIdx.x * 4 + (threadIdx.x >> 6);  // one wave per token
    int lane = threadIdx.x & 63;
    int l = t >> 7, b = t & 127;
    int d = lane * 8;
    float acc[8];
    {
        f32x8 v = *(const f32x8*)(emb32 + (size_t)t * DIM + d);
#pragma unroll
        for (int i = 0; i < 8; i++) acc[i] = v[i];
    }
    const int* bp = bond + ((size_t)b * NL + l) * 6;
#pragma unroll
    for (int m = 0; m < 6; m++) {
        int j = bp[m];
        if (j != l) {  // wave-uniform branch
            u16x8 g = *(const u16x8*)(msg + ((size_t)j * NB + b) * DIM + d);
#pragma unroll
            for (int i = 0; i < 8; i++) acc[i] += bf2f(g[i]);
        }
    }
    f32x8 o;
#pragma unroll
    for (int i = 0; i < 8; i++) o[i] = acc[i];
    *(f32x8*)(out + (size_t)t * DIM + d) = o;
}

extern "C" void kernel_launch(void* const* d_in, const int* in_sizes, int n_in,
                              void* d_out, int out_size, void* d_ws, size_t ws_size,
                              hipStream_t stream) {
    const int* element = (const int*)d_in[0];
    const int* bond    = (const int*)d_in[1];
    const int* aroma   = (const int*)d_in[2];
    const int* charge  = (const int*)d_in[3];
    const int* segment = (const int*)d_in[4];
    const float* pe      = (const float*)d_in[5];
    const float* E_elem  = (const float*)d_in[6];
    const float* E_charge= (const float*)d_in[7];
    const float* E_aroma = (const float*)d_in[8];
    const float* E_seg   = (const float*)d_in[9];
    const float* W1 = (const float*)d_in[10];
    const float* b1 = (const float*)d_in[11];
    const float* W2 = (const float*)d_in[12];
    const float* b2 = (const float*)d_in[13];
    const float* W3 = (const float*)d_in[14];
    const float* b3 = (const float*)d_in[15];
    const float* W4 = (const float*)d_in[16];
    const float* b4 = (const float*)d_in[17];
    const float* W5 = (const float*)d_in[18];
    const float* b5 = (const float*)d_in[19];

    // f32 emb lives in d_out (50 MiB); agg rewrites d_out in place at the end.
    float* emb32 = (float*)d_out;

    // dynamic ws layout — never exceed ws_size
    char* ws = (char*)d_ws;
    size_t woff = 0;
    auto take = [&](size_t bytes) -> u16* {
        u16* p = (u16*)(ws + woff);
        woff += (bytes + 255) & ~(size_t)255;
        return p;
    };
    u16* W1T = take((size_t)HID * DIM * 2);   // 2048x512 bf16
    u16* W2T = take((size_t)DIM * HID * 2);   // 512x2048
    u16* W3T = take((size_t)HID * DIM * 2);
    u16* W4T = take((size_t)DIM * HID * 2);
    u16* W5T = take((size_t)DIM * DIM * 2);
    u16* emb16 = take((size_t)NTOK * DIM * 2);  // 24 MiB
    u16* msg   = take((size_t)NTOK * DIM * 2);  // 24 MiB

    // pick largest M-chunk that fits: h(CM x HID) + xa,xb(CM x DIM), bf16
    static const int ncs[] = {1, 2, 3, 4, 6, 8, 12, 16, 24, 32, 48, 64, 96, 192};
    int CM = 128;
    for (int nc : ncs) {
        int cm = NTOK / nc;
        size_t need = woff + ((size_t)cm * HID * 2 + 256)
                           + ((size_t)cm * DIM * 2 + 256) * 2;
        if (need <= ws_size) { CM = cm; break; }
    }
    u16* hC  = take((size_t)CM * HID * 2);
    u16* xaC = take((size_t)CM * DIM * 2);
    u16* xbC = take((size_t)CM * DIM * 2);

    // weight transposes + cast: f32 (K,N) -> bf16 (N,K)
    transpose_f2b<<<dim3(HID / 32, DIM / 32), 256, 0, stream>>>(W1, W1T, DIM, HID);
    transpose_f2b<<<dim3(DIM / 32, HID / 32), 256, 0, stream>>>(W2, W2T, HID, DIM);
    transpose_f2b<<<dim3(HID / 32, DIM / 32), 256, 0, stream>>>(W3, W3T, DIM, HID);
    transpose_f2b<<<dim3(DIM / 32, HID / 32), 256, 0, stream>>>(W4, W4T, HID, DIM);
    transpose_f2b<<<dim3(DIM / 32, DIM / 32), 256, 0, stream>>>(W5, W5T, DIM, DIM);

    embed_kernel<<<NTOK / 4, 256, 0, stream>>>(element, aroma, charge, segment, pe,
                                               E_elem, E_charge, E_aroma, E_seg,
                                               emb32, emb16);

    // MLP per M-chunk: x += relu(x@W1+b1)@W2+b2 ; x += relu(x@W3+b3)@W4+b4 ; msg = x@W5+b5
    for (int c0 = 0; c0 < NTOK; c0 += CM) {
        const u16* x16 = emb16 + (size_t)c0 * DIM;
        const float* x32 = emb32 + (size_t)c0 * DIM;
        u16* msgC = msg + (size_t)c0 * DIM;
        gemm_bt<<<dim3(CM / 128, HID / 128), 256, 0, stream>>>(x16, W1T, b1, nullptr, nullptr, hC,  CM, HID, DIM, 1);
        gemm_bt<<<dim3(CM / 128, DIM / 128), 256, 0, stream>>>(hC,  W2T, b2, nullptr, x32,     xaC, CM, DIM, HID, 0);
        gemm_bt<<<dim3(CM / 128, HID / 128), 256, 0, stream>>>(xaC, W3T, b3, nullptr, nullptr, hC,  CM, HID, DIM, 1);
        gemm_bt<<<dim3(CM / 128, DIM / 128), 256, 0, stream>>>(hC,  W4T, b4, xaC,    nullptr,  xbC, CM, DIM, HID, 0);
        gemm_bt<<<dim3(CM / 128, DIM / 128), 256, 0, stream>>>(xbC, W5T, b5, nullptr, nullptr, msgC, CM, DIM, DIM, 0);
    }

    agg_kernel<<<NTOK / 4, 256, 0, stream>>>(emb32, msg, bond, (float*)d_out);
}

// Round 6
// 560.073 us; speedup vs baseline: 1.2519x; 1.0959x over previous
//
#include <hip/hip_runtime.h>
#include <cstdint>
#include <cstddef>

typedef unsigned short u16;
typedef unsigned int u32;

typedef unsigned short u16x8 __attribute__((ext_vector_type(8)));
typedef __bf16 bf16x8 __attribute__((ext_vector_type(8)));
typedef float f32x4 __attribute__((ext_vector_type(4)));
typedef float f32x8 __attribute__((ext_vector_type(8)));

#define NB   128
#define NL   192
#define NTOK (NB * NL)   // 24576
#define DIM  512
#define HID  2048

static __device__ __forceinline__ float bf2f(u16 h) {
    union { u32 u; float f; } v; v.u = ((u32)h) << 16; return v.f;
}
static __device__ __forceinline__ u16 f2bf(float f) {
    union { float f; u32 u; } v; v.f = f;
    u32 u = v.u + 0x7FFF + ((v.u >> 16) & 1);  // RNE
    return (u16)(u >> 16);
}

// -------- weight transpose + cast: in f32 (K,N) -> out bf16 (N,K) --------
__global__ void transpose_f2b(const float* __restrict__ in, u16* __restrict__ out,
                              int K, int N) {
    __shared__ float tile[32][33];
    int tx = threadIdx.x & 31, ty = threadIdx.x >> 5;  // 32 x 8
    int n0 = blockIdx.x * 32, k0 = blockIdx.y * 32;
#pragma unroll
    for (int i = 0; i < 4; i++)
        tile[ty + i * 8][tx] = in[(size_t)(k0 + ty + i * 8) * N + n0 + tx];
    __syncthreads();
#pragma unroll
    for (int i = 0; i < 4; i++)
        out[(size_t)(n0 + ty + i * 8) * K + k0 + tx] = f2bf(tile[tx][ty + i * 8]);
}

// -------- embedding: emb[t=l*B+b][d] = sum of 5 f32 tables; f32 + bf16 out ----
static __device__ __forceinline__ void add8f(float* acc, const float* p) {
    f32x8 v = *(const f32x8*)p;
#pragma unroll
    for (int i = 0; i < 8; i++) acc[i] += v[i];
}

__global__ void embed_kernel(const int* __restrict__ element, const int* __restrict__ aroma,
                             const int* __restrict__ charge, const int* __restrict__ segment,
                             const float* __restrict__ pe, const float* __restrict__ E_elem,
                             const float* __restrict__ E_charge, const float* __restrict__ E_aroma,
                             const float* __restrict__ E_seg,
                             float* __restrict__ emb32, u16* __restrict__ emb16) {
    int t = blockIdx.x * 4 + (threadIdx.x >> 6);  // one wave per token
    int lane = threadIdx.x & 63;
    int l = t >> 7, b = t & 127;                  // t = l*128 + b
    int d = lane * 8;
    int idx = b * NL + l;
    int e = element[idx];
    int a = aroma[idx];
    int c = charge[idx] + 6;
    int s = segment[idx];
    float acc[8] = {0, 0, 0, 0, 0, 0, 0, 0};
    add8f(acc, E_elem  + (size_t)e * DIM + d);
    add8f(acc, pe      + (size_t)l * DIM + d);
    add8f(acc, E_aroma + (size_t)a * DIM + d);
    add8f(acc, E_charge+ (size_t)c * DIM + d);
    add8f(acc, E_seg   + (size_t)s * DIM + d);
    f32x8 o32; u16x8 o16;
#pragma unroll
    for (int i = 0; i < 8; i++) { o32[i] = acc[i]; o16[i] = f2bf(acc[i]); }
    *(f32x8*)(emb32 + (size_t)t * DIM + d) = o32;
    *(u16x8*)(emb16 + (size_t)t * DIM + d) = o16;
}

// -------- GEMM: C[M,N] = A[M,K] @ BT[N,K]^T (+f32 bias, relu, bf16/f32 resid) --
// 128x256 block tile, 4 waves each 64x128 (4x8 frags of 16x16x32 MFMA):
// 12 KB LDS reads feed 32 MFMA per wave-iter (1.33x FLOP/LDS-byte vs 4x4).
// Triple-buffered LDS, global_load_lds width=16, prefetch distance 2 tiles:
// wait only own 6 oldest loads (s_waitcnt vmcnt(12)) + raw s_barrier.
// Requires K >= 96 (kIters >= 3); all our K are 512/2048.
__global__ __launch_bounds__(256, 2) void gemm_bt(
    const u16* __restrict__ A, const u16* __restrict__ BT,
    const float* __restrict__ bias, const u16* __restrict__ resid16,
    const float* __restrict__ resid32,
    u16* __restrict__ C, int M, int N, int K, int do_relu) {
    __shared__ __align__(16) u16 As[3][128 * 32];   // 24 KB
    __shared__ __align__(16) u16 Bs[3][256 * 32];   // 48 KB

    const int tid  = threadIdx.x;
    const int wave = tid >> 6;
    const int lane = tid & 63;
    const int m0 = blockIdx.x * 128;
    const int n0 = blockIdx.y * 256;
    const int wm = (wave >> 1) * 64;    // wave's 64-row half
    const int wn = (wave & 1) * 128;    // wave's 128-col half
    const int lr = lane >> 2;           // staging: row within 16-row group
    const int lc = (lane & 3) * 8;      // staging: k-chunk (8 bf16 = 16 B)
    const int fr = lane & 15;           // fragment row/col
    const int fq = lane >> 4;           // fragment k-quad

    f32x4 acc[4][8] = {};

    // wave w stages A rows {w*16+lr, 64+w*16+lr}, B rows {w*16+lr + 0,64,128,192}
    const u16* Ag0 = A  + (size_t)(m0 + wave * 16 + lr) * K + lc;
    const u16* Ag1 = Ag0 + (size_t)64 * K;
    const u16* Bg0 = BT + (size_t)(n0 + wave * 16 + lr) * K + lc;
    const u16* Bg1 = Bg0 + (size_t)64 * K;
    const u16* Bg2 = Bg0 + (size_t)128 * K;
    const u16* Bg3 = Bg0 + (size_t)192 * K;
    const int sA0 = (wave * 16) * 32;          // wave-uniform LDS offsets (u16)
    const int sA1 = (64 + wave * 16) * 32;
    const int sB0 = (wave * 16) * 32;
    const int sB1 = (64 + wave * 16) * 32;
    const int sB2 = (128 + wave * 16) * 32;
    const int sB3 = (192 + wave * 16) * 32;

#define GLL(gp, lp) __builtin_amdgcn_global_load_lds(                            \
        (const __attribute__((address_space(1))) void*)(gp),                     \
        (__attribute__((address_space(3))) void*)(lp), 16, 0, 0)
#define STAGE(buf, k0) do {                                                      \
    GLL(Ag0 + (k0), &As[buf][sA0]);                                              \
    GLL(Ag1 + (k0), &As[buf][sA1]);                                              \
    GLL(Bg0 + (k0), &Bs[buf][sB0]);                                              \
    GLL(Bg1 + (k0), &Bs[buf][sB1]);                                              \
    GLL(Bg2 + (k0), &Bs[buf][sB2]);                                              \
    GLL(Bg3 + (k0), &Bs[buf][sB3]);                                              \
} while (0)

    const int kIters = K >> 5;
    STAGE(0, 0);          // 6 loads in flight
    STAGE(1, 32);         // 12
    STAGE(2, 64);         // 18

    int cur = 0;
    for (int k = 0; k < kIters; ++k) {
        // drain own 6 oldest loads (tile k); tiles k+1,k+2 (12) stay in flight.
        asm volatile("s_waitcnt vmcnt(12)\n\ts_barrier" ::: "memory");

        bf16x8 af[4], bg[8];
#pragma unroll
        for (int i = 0; i < 4; i++)
            af[i] = *(const bf16x8*)(&As[cur][(wm + i * 16 + fr) * 32 + fq * 8]);
#pragma unroll
        for (int j = 0; j < 8; j++)
            bg[j] = *(const bf16x8*)(&Bs[cur][(wn + j * 16 + fr) * 32 + fq * 8]);
#pragma unroll
        for (int i = 0; i < 4; i++)
#pragma unroll
            for (int j = 0; j < 8; j++)
                acc[i][j] = __builtin_amdgcn_mfma_f32_16x16x32_bf16(
                    af[i], bg[j], acc[i][j], 0, 0, 0);

        // all waves done reading buf cur -> safe to overwrite with tile k+3.
        asm volatile("s_barrier" ::: "memory");
        // dummy tail reloads keep vmcnt bookkeeping uniform; they target a
        // buffer that is never read again.
        const int knext = (k + 3 < kIters) ? (k + 3) << 5 : 0;
        STAGE(cur, knext);
        cur = (cur == 2) ? 0 : cur + 1;
    }
#undef STAGE
#undef GLL

    // epilogue: C/D layout col = lane&15 (n), row = (lane>>4)*4 + reg (m)
#pragma unroll
    for (int j = 0; j < 8; j++) {
        int n = n0 + wn + j * 16 + fr;
        float bv = bias[n];
#pragma unroll
        for (int i = 0; i < 4; i++) {
#pragma unroll
            for (int r = 0; r < 4; r++) {
                int m = m0 + wm + i * 16 + fq * 4 + r;
                float v = acc[i][j][r] + bv;
                if (do_relu) v = fmaxf(v, 0.0f);
                if (resid16) v += bf2f(resid16[(size_t)m * N + n]);
                if (resid32) v += resid32[(size_t)m * N + n];
                C[(size_t)m * N + n] = f2bf(v);
            }
        }
    }
}

// -------- aggregation + final residual (in-place on d_out, f32) --------
// out[t=l*B+b][d] = emb32[t][d] + sum_m (bond[b,l,m]!=l) * msg[bond*B+b][d]
__global__ void agg_kernel(const float* __restrict__ emb32, const u16* __restrict__ msg,
                           const int* __restrict__ bond, float* __restrict__ out) {
    int t = blockIdx.x * 4 + (threadIdx.x >> 6);  // one wave per token
    int lane = threadIdx.x & 63;
    int l = t >> 7, b = t & 127;
    int d = lane * 8;
    float acc[8];
    {
        f32x8 v = *(const f32x8*)(emb32 + (size_t)t * DIM + d);
#pragma unroll
        for (int i = 0; i < 8; i++) acc[i] = v[i];
    }
    const int* bp = bond + ((size_t)b * NL + l) * 6;
#pragma unroll
    for (int m = 0; m < 6; m++) {
        int j = bp[m];
        if (j != l) {  // wave-uniform branch
            u16x8 g = *(const u16x8*)(msg + ((size_t)j * NB + b) * DIM + d);
#pragma unroll
            for (int i = 0; i < 8; i++) acc[i] += bf2f(g[i]);
        }
    }
    f32x8 o;
#pragma unroll
    for (int i = 0; i < 8; i++) o[i] = acc[i];
    *(f32x8*)(out + (size_t)t * DIM + d) = o;
}

extern "C" void kernel_launch(void* const* d_in, const int* in_sizes, int n_in,
                              void* d_out, int out_size, void* d_ws, size_t ws_size,
                              hipStream_t stream) {
    const int* element = (const int*)d_in[0];
    const int* bond    = (const int*)d_in[1];
    const int* aroma   = (const int*)d_in[2];
    const int* charge  = (const int*)d_in[3];
    const int* segment = (const int*)d_in[4];
    const float* pe      = (const float*)d_in[5];
    const float* E_elem  = (const float*)d_in[6];
    const float* E_charge= (const float*)d_in[7];
    const float* E_aroma = (const float*)d_in[8];
    const float* E_seg   = (const float*)d_in[9];
    const float* W1 = (const float*)d_in[10];
    const float* b1 = (const float*)d_in[11];
    const float* W2 = (const float*)d_in[12];
    const float* b2 = (const float*)d_in[13];
    const float* W3 = (const float*)d_in[14];
    const float* b3 = (const float*)d_in[15];
    const float* W4 = (const float*)d_in[16];
    const float* b4 = (const float*)d_in[17];
    const float* W5 = (const float*)d_in[18];
    const float* b5 = (const float*)d_in[19];

    // f32 emb lives in d_out (50 MiB); agg rewrites d_out in place at the end.
    float* emb32 = (float*)d_out;

    // dynamic ws layout — never exceed ws_size
    char* ws = (char*)d_ws;
    size_t woff = 0;
    auto take = [&](size_t bytes) -> u16* {
        u16* p = (u16*)(ws + woff);
        woff += (bytes + 255) & ~(size_t)255;
        return p;
    };
    u16* W1T = take((size_t)HID * DIM * 2);   // 2048x512 bf16
    u16* W2T = take((size_t)DIM * HID * 2);   // 512x2048
    u16* W3T = take((size_t)HID * DIM * 2);
    u16* W4T = take((size_t)DIM * HID * 2);
    u16* W5T = take((size_t)DIM * DIM * 2);
    u16* emb16 = take((size_t)NTOK * DIM * 2);  // 24 MiB
    u16* msg   = take((size_t)NTOK * DIM * 2);  // 24 MiB

    // pick largest M-chunk that fits: h(CM x HID) + xa,xb(CM x DIM), bf16
    static const int ncs[] = {1, 2, 3, 4, 6, 8, 12, 16, 24, 32, 48, 64, 96, 192};
    int CM = 128;
    for (int nc : ncs) {
        int cm = NTOK / nc;
        size_t need = woff + ((size_t)cm * HID * 2 + 256)
                           + ((size_t)cm * DIM * 2 + 256) * 2;
        if (need <= ws_size) { CM = cm; break; }
    }
    u16* hC  = take((size_t)CM * HID * 2);
    u16* xaC = take((size_t)CM * DIM * 2);
    u16* xbC = take((size_t)CM * DIM * 2);

    // weight transposes + cast: f32 (K,N) -> bf16 (N,K)
    transpose_f2b<<<dim3(HID / 32, DIM / 32), 256, 0, stream>>>(W1, W1T, DIM, HID);
    transpose_f2b<<<dim3(DIM / 32, HID / 32), 256, 0, stream>>>(W2, W2T, HID, DIM);
    transpose_f2b<<<dim3(HID / 32, DIM / 32), 256, 0, stream>>>(W3, W3T, DIM, HID);
    transpose_f2b<<<dim3(DIM / 32, HID / 32), 256, 0, stream>>>(W4, W4T, HID, DIM);
    transpose_f2b<<<dim3(DIM / 32, DIM / 32), 256, 0, stream>>>(W5, W5T, DIM, DIM);

    embed_kernel<<<NTOK / 4, 256, 0, stream>>>(element, aroma, charge, segment, pe,
                                               E_elem, E_charge, E_aroma, E_seg,
                                               emb32, emb16);

    // MLP per M-chunk: x += relu(x@W1+b1)@W2+b2 ; x += relu(x@W3+b3)@W4+b4 ; msg = x@W5+b5
    for (int c0 = 0; c0 < NTOK; c0 += CM) {
        const u16* x16 = emb16 + (size_t)c0 * DIM;
        const float* x32 = emb32 + (size_t)c0 * DIM;
        u16* msgC = msg + (size_t)c0 * DIM;
        gemm_bt<<<dim3(CM / 128, HID / 256), 256, 0, stream>>>(x16, W1T, b1, nullptr, nullptr, hC,  CM, HID, DIM, 1);
        gemm_bt<<<dim3(CM / 128, DIM / 256), 256, 0, stream>>>(hC,  W2T, b2, nullptr, x32,     xaC, CM, DIM, HID, 0);
        gemm_bt<<<dim3(CM / 128, HID / 256), 256, 0, stream>>>(xaC, W3T, b3, nullptr, nullptr, hC,  CM, HID, DIM, 1);
        gemm_bt<<<dim3(CM / 128, DIM / 256), 256, 0, stream>>>(hC,  W4T, b4, xaC,    nullptr,  xbC, CM, DIM, HID, 0);
        gemm_bt<<<dim3(CM / 128, DIM / 256), 256, 0, stream>>>(xbC, W5T, b5, nullptr, nullptr, msgC, CM, DIM, DIM, 0);
    }

    agg_kernel<<<NTOK / 4, 256, 0, stream>>>(emb32, msg, bond, (float*)d_out);
}